// Round 4
// baseline (234.995 us; speedup 1.0000x reference)
//
#include <hip/hip_runtime.h>
#include <stdint.h>

// ---------------------------------------------------------------------------
// TiledMemristorLinear — exact re-implementation of the JAX reference.
//
// Key numerical facts this code relies on (each verified analytically):
//  * jnp.round == rintf (round-half-to-even).
//  * DAC: v = clip(rint(x*128),-128,128) * (1/128) * 0.6f  (pow2 scaling exact).
//  * johnson/shot ratio <= 3.05e-9 < 2^-25  ->  fl(johnson+shot)==shot in f32,
//    so sigma = sqrt(((2*e)*|raw|)*1e-8f) EXACTLY as the reference computes it.
//  * uniform: (hi-lo) rounds to exactly 2.0f; u = f*2 - 0.99999994f (one rounding).
//  * erfinv: XLA's Giles-2012 polynomial (branches agree to 6e-7 at w=5, so a
//    fast log is safe for w).
//  * noise bits: JAX threefry, partitionable mode (default since jax 0.4.30):
//    bits[e] = y0 ^ y1 of threefry2x32(key, (0, e)).
//  * nkey(c) = threefry2x32((0,42), (0, c)), c = i*4 + j*2 + k.
// ---------------------------------------------------------------------------

struct KeyPack { uint32_t k0[8]; uint32_t k1[8]; };

__host__ __device__ inline void threefry2x32(uint32_t k0, uint32_t k1,
                                             uint32_t x0, uint32_t x1,
                                             uint32_t& y0, uint32_t& y1) {
  const uint32_t ks0 = k0, ks1 = k1, ks2 = k0 ^ k1 ^ 0x1BD11BDAu;
  x0 += ks0; x1 += ks1;
#define TF_ROUND(r) { x0 += x1; x1 = (x1 << (r)) | (x1 >> (32 - (r))); x1 ^= x0; }
  TF_ROUND(13) TF_ROUND(15) TF_ROUND(26) TF_ROUND(6)
  x0 += ks1; x1 += ks2 + 1u;
  TF_ROUND(17) TF_ROUND(29) TF_ROUND(16) TF_ROUND(24)
  x0 += ks2; x1 += ks0 + 2u;
  TF_ROUND(13) TF_ROUND(15) TF_ROUND(26) TF_ROUND(6)
  x0 += ks0; x1 += ks1 + 3u;
  TF_ROUND(17) TF_ROUND(29) TF_ROUND(16) TF_ROUND(24)
  x0 += ks1; x1 += ks2 + 4u;
  TF_ROUND(13) TF_ROUND(15) TF_ROUND(26) TF_ROUND(6)
  x0 += ks2; x1 += ks0 + 5u;
#undef TF_ROUND
  y0 = x0; y1 = x1;
}

// bits -> N(0,1) float, matching XLA: u in [lo, 1) via mantissa trick, then
// sqrt(2)*erfinv(u) with XLA's exact polynomial constants.
__device__ inline float bits_to_normal(uint32_t bits) {
  float f = __uint_as_float((bits >> 9) | 0x3f800000u) - 1.0f;   // [0,1), exact
  float u = fmaxf(fmaf(f, 2.0f, -0.99999994f), -0.99999994f);    // (hi-lo)==2.0f exactly
  // w = -log1p(-u*u); 1-u*u is Sterbenz-exact for u*u>=0.5, and for small u*u
  // the absolute error of the fast log is << 1e-7 -> harmless (tolerance 2e-3).
  float w = -__logf(1.0f - u * u);
  float p;
  if (w < 5.0f) {
    w -= 2.5f;
    p = 2.81022636e-08f;
    p = fmaf(p, w, 3.43273939e-07f);
    p = fmaf(p, w, -3.5233877e-06f);
    p = fmaf(p, w, -4.39150654e-06f);
    p = fmaf(p, w, 0.00021858087f);
    p = fmaf(p, w, -0.00125372503f);
    p = fmaf(p, w, -0.00417768164f);
    p = fmaf(p, w, 0.246640727f);
    p = fmaf(p, w, 1.50140941f);
  } else {                       // ~0.3% of lanes; branches agree to 6e-7 at w=5
    w = __builtin_amdgcn_sqrtf(w) - 3.0f;
    p = -0.000200214257f;
    p = fmaf(p, w, 0.000100950558f);
    p = fmaf(p, w, 0.00134934322f);
    p = fmaf(p, w, -0.00367342844f);
    p = fmaf(p, w, 0.00573950773f);
    p = fmaf(p, w, -0.0076224613f);
    p = fmaf(p, w, 0.00943887047f);
    p = fmaf(p, w, 1.00167406f);
    p = fmaf(p, w, 2.83297682f);
  }
  return 1.41421354f * (p * u);  // fl(sqrt(2)) * erfinv
}

// out[b,t,o] = bias[o]  (bias added first; order diff vs ref ~1 ulp of 48)
__global__ void memristor_init(const float* __restrict__ bias,
                               float* __restrict__ out) {
  int idx = blockIdx.x * 256 + threadIdx.x;
  out[idx] = bias[idx & 255];
}

// One block = one (combo c = i*4+j*2+k, t). 256 threads: mo = tid&127,
// mi-half = tid>>7. Each thread walks 64 mi values; per mi: 2 threefry
// ciphers (p=0/p=1 noise element), 2 erfinv, 8 lerp/sigma/accumulate chains.
__global__ __launch_bounds__(256, 4)
void memristor_main(const float* __restrict__ x,
                    const float* __restrict__ poly_low,
                    const float* __restrict__ poly_high,
                    const float* __restrict__ r,
                    float* __restrict__ out,
                    KeyPack keys) {
  __shared__ __align__(16) float LH[128][16];  // [mi][p*4+b]=low, [8+p*4+b]=high
  __shared__ float RED[128][8];

  const int tid = threadIdx.x;
  const int bid = blockIdx.x;
  const int c = bid >> 8;                 // 0..7
  const int t = bid & 255;
  const int j = (c >> 1) & 1;
  const int k = c & 1;
  const float iscale = (c & 4) ? 1.0f : 2.0f;   // i==0 -> bit=1 -> *2

  // ---- per-(p,b,mi) polynomial table (reused 128x over mo) ----
  for (int task = tid; task < 1024; task += 256) {
    int mi = task & 127;
    int pb = task >> 7;                   // 0..7
    int p = pb >> 2, b = pb & 3;
    float xv = x[(b * 256 + t) * 256 + j * 128 + mi];
    float q = rintf(xv * 128.0f);
    q = fminf(fmaxf(q, -128.0f), 128.0f);
    float v = (q * 0.0078125f) * 0.6f;    // exact pow2 scale, then one rounding
    const float* cl = poly_low + (c * 2 + p) * 7;
    float lo = cl[6];
    #pragma unroll
    for (int n = 5; n >= 0; --n) lo = fmaf(lo, v, cl[n]);
    const float* ch = poly_high + (c * 2 + p) * 6;
    float hi = ch[5];
    #pragma unroll
    for (int n = 4; n >= 0; --n) hi = fmaf(hi, v, ch[n]);
    LH[mi][p * 4 + b] = lo;
    LH[mi][8 + p * 4 + b] = hi;
  }
  __syncthreads();

  const int mo = tid & 127;
  const int mih = tid >> 7;
  const int miBase = mih * 64;
  const uint32_t k0 = keys.k0[c], k1 = keys.k1[c];
  const float* r0p = r + c * 32768 + miBase * 128 + mo;   // p=0 slice
  const float* r1p = r0p + 16384;                         // p=1 slice
  uint32_t s = (uint32_t)(t * 16384 + miBase * 128 + mo); // noise flat idx (p=0)

  float acc[8];
  #pragma unroll
  for (int v2 = 0; v2 < 8; ++v2) acc[v2] = 0.0f;

  const float SHOT_C = (float)(2.0 * 2.718281828459045);  // fl(2*e)

  #pragma unroll 2
  for (int ii = 0; ii < 64; ++ii) {
    int mi = miBase + ii;
    const float4* lh4 = (const float4*)(&LH[mi][0]);
    float4 L0 = lh4[0];   // low  p=0, b=0..3
    float4 L1 = lh4[1];   // low  p=1
    float4 H0 = lh4[2];   // high p=0
    float4 H1 = lh4[3];   // high p=1
    float r0 = r0p[ii * 128];
    float r1 = r1p[ii * 128];

    uint32_t y0, y1;
    threefry2x32(k0, k1, 0u, s, y0, y1);
    float n0 = bits_to_normal(y0 ^ y1);
    threefry2x32(k0, k1, 0u, s + 4194304u, y0, y1);   // p=1 block offset 2*T*MI*MO/2
    float n1 = bits_to_normal(y0 ^ y1);
    s += 128u;                                        // next mi

    float omr0 = 1.0f - r0;
    float omr1 = 1.0f - r1;
    {
      float raws[4] = { fmaf(L0.x, omr0, H0.x * r0), fmaf(L0.y, omr0, H0.y * r0),
                        fmaf(L0.z, omr0, H0.z * r0), fmaf(L0.w, omr0, H0.w * r0) };
      #pragma unroll
      for (int b = 0; b < 4; ++b) {
        float raw = raws[b];
        float sig = __builtin_amdgcn_sqrtf((SHOT_C * fabsf(raw)) * 1e-8f);
        acc[b] += fmaf(n0, sig, raw);
      }
    }
    {
      float raws[4] = { fmaf(L1.x, omr1, H1.x * r1), fmaf(L1.y, omr1, H1.y * r1),
                        fmaf(L1.z, omr1, H1.z * r1), fmaf(L1.w, omr1, H1.w * r1) };
      #pragma unroll
      for (int b = 0; b < 4; ++b) {
        float raw = raws[b];
        float sig = __builtin_amdgcn_sqrtf((SHOT_C * fabsf(raw)) * 1e-8f);
        acc[4 + b] += fmaf(n1, sig, raw);
      }
    }
  }

  // ---- combine mi-halves, ADC, accumulate ----
  if (mih == 1) {
    #pragma unroll
    for (int v2 = 0; v2 < 8; ++v2) RED[mo][v2] = acc[v2];
  }
  __syncthreads();
  if (mih == 0) {
    #pragma unroll
    for (int v2 = 0; v2 < 8; ++v2) acc[v2] += RED[mo][v2];
    #pragma unroll
    for (int b = 0; b < 4; ++b) {
      float pair = acc[b] - acc[4 + b];                 // p0 - p1
      float q = rintf((pair * 8020.0f) * 256.0f);       // /ADC_SCALE is *256, exact
      q = fminf(fmaxf(q, -2048.0f), 2048.0f);
      float contrib = (q * 0.00390625f) * iscale;
      atomicAdd(&out[(b * 256 + t) * 256 + k * 128 + mo], contrib);
    }
  }
}

extern "C" void kernel_launch(void* const* d_in, const int* in_sizes, int n_in,
                              void* d_out, int out_size, void* d_ws, size_t ws_size,
                              hipStream_t stream) {
  const float* x    = (const float*)d_in[0];
  const float* pl   = (const float*)d_in[1];
  const float* ph   = (const float*)d_in[2];
  const float* r    = (const float*)d_in[3];
  const float* bias = (const float*)d_in[4];
  float* out = (float*)d_out;

  // nkey(c) = fold_in(key(42), c) = threefry2x32((0,42), (0,c))
  KeyPack keys;
  for (uint32_t cc = 0; cc < 8; ++cc) {
    uint32_t y0, y1;
    threefry2x32(0u, 42u, 0u, cc, y0, y1);
    keys.k0[cc] = y0; keys.k1[cc] = y1;
  }

  memristor_init<<<1024, 256, 0, stream>>>(bias, out);
  memristor_main<<<2048, 256, 0, stream>>>(x, pl, ph, r, out, keys);
}

// Round 5
// 223.543 us; speedup vs baseline: 1.0512x; 1.0512x over previous
//
#include <hip/hip_runtime.h>
#include <stdint.h>

// ---------------------------------------------------------------------------
// TiledMemristorLinear — exact re-implementation of the JAX reference.
//
// Numerical contract (all verified analytically; kernel passed at absmax
// = 1 output LSB with the stricter round-3 formulation):
//  * jnp.round == rintf; DAC/ADC pow2 scalings are exact (commute with fl()).
//  * johnson/shot <= 3e-9 < 2^-25 -> sigma = sqrt((2e*BW)*|raw|) bit-equal.
//  * noise bits: JAX partitionable threefry: bits[e] = y0^y1 of
//    threefry2x32(key, (0, e));  nkey(c) = threefry2x32((0,42),(0,c)).
//  * erfinv: XLA Giles-2012 polynomials, sqrt(2) folded into coefficients
//    (<= couple-ulp drift in n; output grid is 243 LSB of noise -> only
//    rare quantization-boundary flips, absmax threshold 0.96).
//  * lerp refactor raw = fma(H-L, r, L) and fused 1-u^2: ulp-level drift,
//    same argument.
// This round is pure VALU-instruction-count reduction (kernel is issue-bound:
// VALUBusy ~106%, HBM 0.4%).
// ---------------------------------------------------------------------------

struct KeyPack { uint32_t k0[8]; uint32_t k1[8]; uint32_t k2[8]; };

// rotl via v_alignbit_b32: alignbit(x,x,32-r) == (x<<r)|(x>>(32-r))
#define TFR(r) { x0 += x1; x1 = __builtin_amdgcn_alignbit(x1, x1, 32u - (r)); x1 ^= x0; }

// Threefry-2x32, counter (0, ctr). Caller passes x1 = ctr + ks1 (pre-biased);
// x0 = 0 + ks0. Returns y0 ^ y1 (JAX partitionable bits).
__device__ __forceinline__ uint32_t tf_bits(uint32_t ks0, uint32_t ks1,
                                            uint32_t ks2, uint32_t x1) {
  uint32_t x0 = ks0;
  TFR(13) TFR(15) TFR(26) TFR(6)
  x0 += ks1; x1 += ks2 + 1u;
  TFR(17) TFR(29) TFR(16) TFR(24)
  x0 += ks2; x1 += ks0 + 2u;
  TFR(13) TFR(15) TFR(26) TFR(6)
  x0 += ks0; x1 += ks1 + 3u;
  TFR(17) TFR(29) TFR(16) TFR(24)
  x0 += ks1; x1 += ks2 + 4u;
  TFR(13) TFR(15) TFR(26) TFR(6)
  x0 += ks2; x1 += ks0 + 5u;
  return x0 ^ x1;
}

__host__ __device__ inline void threefry2x32_host(uint32_t k0, uint32_t k1,
                                                  uint32_t x0, uint32_t x1,
                                                  uint32_t& y0, uint32_t& y1) {
  const uint32_t ks0 = k0, ks1 = k1, ks2 = k0 ^ k1 ^ 0x1BD11BDAu;
  x0 += ks0; x1 += ks1;
#define TF_ROUND(r) { x0 += x1; x1 = (x1 << (r)) | (x1 >> (32 - (r))); x1 ^= x0; }
  TF_ROUND(13) TF_ROUND(15) TF_ROUND(26) TF_ROUND(6)
  x0 += ks1; x1 += ks2 + 1u;
  TF_ROUND(17) TF_ROUND(29) TF_ROUND(16) TF_ROUND(24)
  x0 += ks2; x1 += ks0 + 2u;
  TF_ROUND(13) TF_ROUND(15) TF_ROUND(26) TF_ROUND(6)
  x0 += ks0; x1 += ks1 + 3u;
  TF_ROUND(17) TF_ROUND(29) TF_ROUND(16) TF_ROUND(24)
  x0 += ks1; x1 += ks2 + 4u;
  TF_ROUND(13) TF_ROUND(15) TF_ROUND(26) TF_ROUND(6)
  x0 += ks2; x1 += ks0 + 5u;
#undef TF_ROUND
  y0 = x0; y1 = x1;
}

// bits -> sqrt(2)*erfinv(uniform), sqrt(2) folded into the polynomials.
__device__ __forceinline__ float bits_to_normal(uint32_t bits) {
  // g in [1,2): one v_alignbit builds (bits>>9)|0x3f800000
  float g = __uint_as_float(__builtin_amdgcn_alignbit(0x7Fu, bits, 9u));
  // u = (g-1)*2 - 0.99999994 folded to fma(g,2,-3): systematic 6e-8 shift, safe
  float u = fmaxf(fmaf(g, 2.0f, -3.0f), -0.99999994f);
  float w = -__logf(fmaf(u, -u, 1.0f));      // -log(1-u^2), fused
  float p;
  if (w < 5.0f) {
    w -= 2.5f;
    p = (float)(2.81022636e-08 * 1.4142135623730951);
    p = fmaf(p, w, (float)( 3.43273939e-07 * 1.4142135623730951));
    p = fmaf(p, w, (float)(-3.5233877e-06  * 1.4142135623730951));
    p = fmaf(p, w, (float)(-4.39150654e-06 * 1.4142135623730951));
    p = fmaf(p, w, (float)( 0.00021858087  * 1.4142135623730951));
    p = fmaf(p, w, (float)(-0.00125372503  * 1.4142135623730951));
    p = fmaf(p, w, (float)(-0.00417768164  * 1.4142135623730951));
    p = fmaf(p, w, (float)( 0.246640727    * 1.4142135623730951));
    p = fmaf(p, w, (float)( 1.50140941     * 1.4142135623730951));
  } else {                         // ~0.3% of lanes
    w = __builtin_amdgcn_sqrtf(w) - 3.0f;
    p = (float)(-0.000200214257 * 1.4142135623730951);
    p = fmaf(p, w, (float)( 0.000100950558 * 1.4142135623730951));
    p = fmaf(p, w, (float)( 0.00134934322  * 1.4142135623730951));
    p = fmaf(p, w, (float)(-0.00367342844  * 1.4142135623730951));
    p = fmaf(p, w, (float)( 0.00573950773  * 1.4142135623730951));
    p = fmaf(p, w, (float)(-0.0076224613   * 1.4142135623730951));
    p = fmaf(p, w, (float)( 0.00943887047  * 1.4142135623730951));
    p = fmaf(p, w, (float)( 1.00167406     * 1.4142135623730951));
    p = fmaf(p, w, (float)( 2.83297682     * 1.4142135623730951));
  }
  return p * u;
}

// out[b,t,o] = bias[o]  (bias first; commutation diff ~1 ulp, tolerated)
__global__ void memristor_init(const float* __restrict__ bias,
                               float* __restrict__ out) {
  int idx = blockIdx.x * 256 + threadIdx.x;
  out[idx] = bias[idx & 255];
}

// One block = one (combo c = i*4+j*2+k, t). 256 threads: mo = tid&127,
// mi-half = tid>>7, 64 mi per thread. Per mi: 2 threefry ciphers, 2 erfinv,
// 8 {fma-lerp, sqrt-sigma, fma+add accumulate} chains.
__global__ __launch_bounds__(256, 4)
void memristor_main(const float* __restrict__ x,
                    const float* __restrict__ poly_low,
                    const float* __restrict__ poly_high,
                    const float* __restrict__ r,
                    float* __restrict__ out,
                    KeyPack keys) {
  __shared__ __align__(16) float LH[128][16];  // [mi][p*4+b]=L, [8+p*4+b]=H-L
  __shared__ float RED[128][9];                // pad 9: conflict-free b32

  const int tid = threadIdx.x;
  const int bid = blockIdx.x;
  const int c = bid >> 8;                 // 0..7
  const int t = bid & 255;
  const int j = (c >> 1) & 1;
  const int k = c & 1;

  // ---- per-(p,b,mi) polynomial table (reused 128x over mo) ----
  // task mapping pb=task&7 keeps LDS writes ~4-way instead of 32-way.
  for (int task = tid; task < 1024; task += 256) {
    int pb = task & 7;                    // p*4+b
    int mi = task >> 3;
    int p = pb >> 2, b = pb & 3;
    float xv = x[(b * 256 + t) * 256 + j * 128 + mi];
    float q = rintf(xv * 128.0f);
    q = fminf(fmaxf(q, -128.0f), 128.0f);
    float v = (q * 0.0078125f) * 0.6f;    // exact pow2 scale, then one rounding
    const float* cl = poly_low + (c * 2 + p) * 7;
    float lo = cl[6];
    #pragma unroll
    for (int n = 5; n >= 0; --n) lo = fmaf(lo, v, cl[n]);
    const float* ch = poly_high + (c * 2 + p) * 6;
    float hi = ch[5];
    #pragma unroll
    for (int n = 4; n >= 0; --n) hi = fmaf(hi, v, ch[n]);
    LH[mi][pb] = lo;
    LH[mi][8 + pb] = hi - lo;             // D = H - L  (raw = fma(D, r, L))
  }
  __syncthreads();

  const int mo = tid & 127;
  const int mih = tid >> 7;
  const int miBase = mih * 64;
  const uint32_t k0 = keys.k0[c], k1 = keys.k1[c], k2 = keys.k2[c];
  const float* r0p = r + c * 32768 + miBase * 128 + mo;   // p=0 slice
  const float* r1p = r0p + 16384;                         // p=1 slice
  // counter pre-biased by ks1: x1_init = flatidx + ks1
  uint32_t sk = (uint32_t)(t * 16384 + miBase * 128 + mo) + k1;

  float acc[8];
  #pragma unroll
  for (int v2 = 0; v2 < 8; ++v2) acc[v2] = 0.0f;

  // KS = fl( fl32(2*e) * fl32(1e-8) ): folded sigma constant (<=1 ulp vs ref)
  const float KS = (float)((double)((float)(2.0 * 2.718281828459045)) *
                           (double)(1e-8f));

  #pragma unroll 2
  for (int ii = 0; ii < 64; ++ii) {
    const float4* lh4 = (const float4*)(&LH[miBase + ii][0]);
    float4 L0 = lh4[0];   // L p=0, b=0..3
    float4 L1 = lh4[1];   // L p=1
    float4 D0 = lh4[2];   // H-L p=0
    float4 D1 = lh4[3];   // H-L p=1
    float r0 = r0p[ii * 128];
    float r1 = r1p[ii * 128];

    uint32_t b0 = tf_bits(k0, k1, k2, sk);              // p=0 element
    uint32_t b1 = tf_bits(k0, k1, k2, sk + 4194304u);   // p=1 (+2*T*MI*MO/2... block offset)
    float n0 = bits_to_normal(b0);
    float n1 = bits_to_normal(b1);
    sk += 128u;                                         // next mi

    // grouped raws -> sigs -> accumulates (SLP-friendly)
    float raw0 = fmaf(D0.x, r0, L0.x);
    float raw1 = fmaf(D0.y, r0, L0.y);
    float raw2 = fmaf(D0.z, r0, L0.z);
    float raw3 = fmaf(D0.w, r0, L0.w);
    float raw4 = fmaf(D1.x, r1, L1.x);
    float raw5 = fmaf(D1.y, r1, L1.y);
    float raw6 = fmaf(D1.z, r1, L1.z);
    float raw7 = fmaf(D1.w, r1, L1.w);

    float s0 = __builtin_amdgcn_sqrtf(KS * fabsf(raw0));
    float s1 = __builtin_amdgcn_sqrtf(KS * fabsf(raw1));
    float s2 = __builtin_amdgcn_sqrtf(KS * fabsf(raw2));
    float s3 = __builtin_amdgcn_sqrtf(KS * fabsf(raw3));
    float s4 = __builtin_amdgcn_sqrtf(KS * fabsf(raw4));
    float s5 = __builtin_amdgcn_sqrtf(KS * fabsf(raw5));
    float s6 = __builtin_amdgcn_sqrtf(KS * fabsf(raw6));
    float s7 = __builtin_amdgcn_sqrtf(KS * fabsf(raw7));

    acc[0] += fmaf(n0, s0, raw0);
    acc[1] += fmaf(n0, s1, raw1);
    acc[2] += fmaf(n0, s2, raw2);
    acc[3] += fmaf(n0, s3, raw3);
    acc[4] += fmaf(n1, s4, raw4);
    acc[5] += fmaf(n1, s5, raw5);
    acc[6] += fmaf(n1, s6, raw6);
    acc[7] += fmaf(n1, s7, raw7);
  }

  // ---- combine mi-halves, ADC, accumulate ----
  if (mih == 1) {
    #pragma unroll
    for (int v2 = 0; v2 < 8; ++v2) RED[mo][v2] = acc[v2];
  }
  __syncthreads();
  if (mih == 0) {
    #pragma unroll
    for (int v2 = 0; v2 < 8; ++v2) acc[v2] += RED[mo][v2];
    // (pair*8020)*256 == pair*2053120 exactly (pow2 scaling commutes with fl)
    const float QSC = 2053120.0f;
    const float OSC = (c & 4) ? 0.00390625f : 0.0078125f;  // ADC_SCALE * 2^bit, exact
    #pragma unroll
    for (int b = 0; b < 4; ++b) {
      float pair = acc[b] - acc[4 + b];                 // p0 - p1
      float q = rintf(pair * QSC);
      q = fminf(fmaxf(q, -2048.0f), 2048.0f);
      atomicAdd(&out[(b * 256 + t) * 256 + k * 128 + mo], q * OSC);
    }
  }
}

extern "C" void kernel_launch(void* const* d_in, const int* in_sizes, int n_in,
                              void* d_out, int out_size, void* d_ws, size_t ws_size,
                              hipStream_t stream) {
  const float* x    = (const float*)d_in[0];
  const float* pl   = (const float*)d_in[1];
  const float* ph   = (const float*)d_in[2];
  const float* r    = (const float*)d_in[3];
  const float* bias = (const float*)d_in[4];
  float* out = (float*)d_out;

  // nkey(c) = fold_in(key(42), c) = threefry2x32((0,42), (0,c))
  KeyPack keys;
  for (uint32_t cc = 0; cc < 8; ++cc) {
    uint32_t y0, y1;
    threefry2x32_host(0u, 42u, 0u, cc, y0, y1);
    keys.k0[cc] = y0; keys.k1[cc] = y1;
    keys.k2[cc] = y0 ^ y1 ^ 0x1BD11BDAu;
  }

  memristor_init<<<1024, 256, 0, stream>>>(bias, out);
  memristor_main<<<2048, 256, 0, stream>>>(x, pl, ph, r, out, keys);
}